// Round 16
// baseline (148.882 us; speedup 1.0000x reference)
//
#include <hip/hip_runtime.h>

// ---------------------------------------------------------------------------
// MultiHeadedAttention: x[8,1024,768] @ w_in[768,2304] -> qkv -> 12-head attn
// (scale = 768^-0.5) -> concat -> @ w_out[768,768] + b_out. f32 in/out,
// bf16 MFMA internally. R16 = R14 with the f32->bf16 cast of x fused into
// gemm1 via a 3-STAGE register pipeline (loads for A(t+2) issued at t,
// cvt+ds_write of A(t+1) in the stage slot at t, consumed at t+1) — fixes
// R10's same-iteration latency exposure. B path and gemm2 keep the proven
// R8 gload_lds counted-vmcnt structure. Attn identical to R14. prep is now
// transposes-only (x-cast kernel and its 36 MB round-trip eliminated).
// ---------------------------------------------------------------------------

using short8 = __attribute__((ext_vector_type(8))) short;  // 8 bf16 (4 VGPR)
using f32x4  = __attribute__((ext_vector_type(4))) float;  // MFMA acc

#define MFMA_B16(a, b, c) __builtin_amdgcn_mfma_f32_16x16x32_bf16((a), (b), (c), 0, 0, 0)

typedef const __attribute__((address_space(1))) void* gvoid_p;
typedef __attribute__((address_space(3))) void* lvoid_p;

constexpr int   kDim   = 768;
constexpr int   kHeads = 12;
constexpr int   kSeq   = 1024;
constexpr float kScale = 0.03608439182435161f;             // 768^-0.5 (full dim)
constexpr float kQSc   = kScale * 1.4426950408889634f;     // fold log2(e) into Q

__device__ __forceinline__ short f2bf(float f) {  // RNE f32 -> bf16 bits
  unsigned u = __float_as_uint(f);
  u += 0x7FFFu + ((u >> 16) & 1u);
  return (short)(u >> 16);
}
__device__ __forceinline__ unsigned cvt_pk_bf16(float lo, float hi) {
  unsigned r;
  asm("v_cvt_pk_bf16_f32 %0, %1, %2" : "=v"(r) : "v"(lo), "v"(hi));
  return r;
}
union U8 { unsigned u[4]; short8 s; };

// ---------- prep: weight transposes only (x-cast is fused into gemm1) ------
// blocks 0..1727: w_in^T ; 1728..2303: w_out^T
__global__ __launch_bounds__(256) void prep_kernel(const float* __restrict__ w_in,
                                                   short* __restrict__ WinT,
                                                   const float* __restrict__ w_out,
                                                   short* __restrict__ WoutT) {
  __shared__ float tile[32][33];
  const int bid = blockIdx.x;
  const float* in; short* out; int R, C, bx, by;
  if (bid < 1728) {
    in = w_in; out = WinT; R = 768; C = 2304; bx = bid % 72; by = bid / 72;
  } else {
    const int b2 = bid - 1728;
    in = w_out; out = WoutT; R = 768; C = 768; bx = b2 % 24; by = b2 / 24;
  }
  const int c0 = bx * 32, r0 = by * 32;
  const int tx = threadIdx.x & 31, ty = threadIdx.x >> 5;
#pragma unroll
  for (int i = 0; i < 32; i += 8)
    tile[ty + i][tx] = in[(size_t)(r0 + ty + i) * C + c0 + tx];
  __syncthreads();
#pragma unroll
  for (int i = 0; i < 32; i += 8)
    out[(size_t)(c0 + ty + i) * R + r0 + tx] = f2bf(tile[tx][ty + i]);
}

// ---------- 128x128 MFMA GEMM, BK=32, 4 waves, 3-buf counted-vmcnt ---------
// AMODE 0: A = f32 (x). 3-stage reg pipeline: iter t issues f32 loads for
//          A(t+2) (alternating reg sets, statically indexed), cvt+ds_write of
//          A(t+1) in the stage slot (loads have a full iteration to land),
//          compute reads A(t). B staged via gload_lds, 2-deep.
// AMODE 1: A = bf16 — exact R8 path (gload_lds A+B, vmcnt 8/4/0).
template <int AMODE, int EPI>
__global__ __launch_bounds__(256) void gemm_tile(const float* __restrict__ Af,
                                                 const short* __restrict__ A,
                                                 const short* __restrict__ BT,
                                                 int Kd,
                                                 short* __restrict__ Qb,
                                                 short* __restrict__ Kb,
                                                 short* __restrict__ VTb,
                                                 const float* __restrict__ bias,
                                                 float* __restrict__ outF) {
  __shared__ short As[3][128 * 32];
  __shared__ short Bs[3][128 * 32];

  const int tid  = threadIdx.x;
  const int lane = tid & 63, w = tid >> 6;
  const int L = lane & 15, g = lane >> 4;
  const int wr = w >> 1, wc = w & 1;
  const int m0 = blockIdx.x * 128, n0 = blockIdx.y * 128;

  const int r4 = lane >> 2;        // row within 16-row chunk (gload_lds)
  const int c8 = (lane & 3) * 8;   // k-col (shorts, gload_lds)

  const int arow = tid >> 1;       // reg-staged A: row 0..127
  const int ac16 = (tid & 1) * 16; // 16 f32 per thread

  auto stageB = [&](int buf, int k0) {  // 2 gload_lds per wave
#pragma unroll
    for (int c = 0; c < 2; ++c) {
      const short* bg = BT + (size_t)(n0 + w * 32 + c * 16 + r4) * Kd + k0 + c8;
      __builtin_amdgcn_global_load_lds((gvoid_p)bg, (lvoid_p)&Bs[buf][(w * 2 + c) * 512], 16, 0, 0);
    }
  };
  auto stageA1 = [&](int buf, int k0) {  // AMODE1: 2 gload_lds per wave
#pragma unroll
    for (int c = 0; c < 2; ++c) {
      const short* ag = A + (size_t)(m0 + w * 32 + c * 16 + r4) * Kd + k0 + c8;
      __builtin_amdgcn_global_load_lds((gvoid_p)ag, (lvoid_p)&As[buf][(w * 2 + c) * 512], 16, 0, 0);
    }
  };

  f32x4 acc[4][4] = {};
  const int NT = Kd / 32;

  auto compute = [&](int cur) {
    short8 af[4], bfr[4];
#pragma unroll
    for (int mi = 0; mi < 4; ++mi)
      af[mi] = *(const short8*)&As[cur][(wr * 64 + mi * 16 + L) * 32 + g * 8];
#pragma unroll
    for (int ni = 0; ni < 4; ++ni)
      bfr[ni] = *(const short8*)&Bs[cur][(wc * 64 + ni * 16 + L) * 32 + g * 8];
#pragma unroll
    for (int mi = 0; mi < 4; ++mi)
#pragma unroll
      for (int ni = 0; ni < 4; ++ni)
        acc[mi][ni] = MFMA_B16(af[mi], bfr[ni], acc[mi][ni]);
  };

  if constexpr (AMODE == 1) {
    // ---- exact R8 loop ----
    stageA1(0, 0); stageB(0, 0);
    stageA1(1, 32); stageB(1, 32);
    for (int t = 0; t < NT; ++t) {
      const int cur = t % 3;
      if (t + 2 < NT) { stageA1((t + 2) % 3, (t + 2) * 32); stageB((t + 2) % 3, (t + 2) * 32); }
      if (t + 2 < NT)      asm volatile("s_waitcnt vmcnt(8)" ::: "memory");
      else if (t + 1 < NT) asm volatile("s_waitcnt vmcnt(4)" ::: "memory");
      else                 asm volatile("s_waitcnt vmcnt(0)" ::: "memory");
      __builtin_amdgcn_s_barrier();
      compute(cur);
      asm volatile("" ::: "memory");
      __builtin_amdgcn_s_barrier();
    }
  } else {
    // ---- 3-stage fused-cast pipeline (NT must be even; 768/32 = 24) ----
    float4 F0[4], F1[4];
    stageB(0, 0);
    stageB(1, 32);
    {
      const float* ap1 = Af + (size_t)(m0 + arow) * Kd + 32 + ac16;
      F1[0] = ((const float4*)ap1)[0]; F1[1] = ((const float4*)ap1)[1];
      F1[2] = ((const float4*)ap1)[2]; F1[3] = ((const float4*)ap1)[3];
      const float* ap0 = Af + (size_t)(m0 + arow) * Kd + ac16;
      F0[0] = ((const float4*)ap0)[0]; F0[1] = ((const float4*)ap0)[1];
      F0[2] = ((const float4*)ap0)[2]; F0[3] = ((const float4*)ap0)[3];
      uint4 d0, d1;
      d0.x = cvt_pk_bf16(F0[0].x, F0[0].y); d0.y = cvt_pk_bf16(F0[0].z, F0[0].w);
      d0.z = cvt_pk_bf16(F0[1].x, F0[1].y); d0.w = cvt_pk_bf16(F0[1].z, F0[1].w);
      d1.x = cvt_pk_bf16(F0[2].x, F0[2].y); d1.y = cvt_pk_bf16(F0[2].z, F0[2].w);
      d1.z = cvt_pk_bf16(F0[3].x, F0[3].y); d1.w = cvt_pk_bf16(F0[3].z, F0[3].w);
      short* dst = &As[0][arow * 32 + ac16];
      *(uint4*)dst = d0; *(uint4*)(dst + 8) = d1;
    }
    asm volatile("s_waitcnt vmcnt(0) lgkmcnt(0)" ::: "memory");
    __builtin_amdgcn_s_barrier();

    auto body = [&](int t, float4 (&Fl)[4], float4 (&Fu)[4]) {
      if (t + 2 < NT) {
        stageB((t + 2) % 3, (t + 2) * 32);
        const float* ap = Af + (size_t)(m0 + arow) * Kd + (t + 2) * 32 + ac16;
        Fl[0] = ((const float4*)ap)[0]; Fl[1] = ((const float4*)ap)[1];
        Fl[2] = ((const float4*)ap)[2]; Fl[3] = ((const float4*)ap)[3];
      }
      if (t + 1 < NT) {
        // consumes loads issued one full iteration ago (latency hidden);
        // implicit reg-dep vmcnt also drains stageB(t+1) -> B(t) landed.
        uint4 d0, d1;
        d0.x = cvt_pk_bf16(Fu[0].x, Fu[0].y); d0.y = cvt_pk_bf16(Fu[0].z, Fu[0].w);
        d0.z = cvt_pk_bf16(Fu[1].x, Fu[1].y); d0.w = cvt_pk_bf16(Fu[1].z, Fu[1].w);
        d1.x = cvt_pk_bf16(Fu[2].x, Fu[2].y); d1.y = cvt_pk_bf16(Fu[2].z, Fu[2].w);
        d1.z = cvt_pk_bf16(Fu[3].x, Fu[3].y); d1.w = cvt_pk_bf16(Fu[3].z, Fu[3].w);
        short* dst = &As[(t + 1) % 3][arow * 32 + ac16];
        *(uint4*)dst = d0; *(uint4*)(dst + 8) = d1;
      }
      if (t + 2 < NT) asm volatile("s_waitcnt vmcnt(6)" ::: "memory");
      else            asm volatile("s_waitcnt vmcnt(0)" ::: "memory");
      asm volatile("s_waitcnt lgkmcnt(0)" ::: "memory");  // ds_writes visible
      __builtin_amdgcn_s_barrier();   // tile t (A write + B gload) ready
      compute(t % 3);
      asm volatile("" ::: "memory");
      __builtin_amdgcn_s_barrier();   // reads done before buffer reuse
    };
    for (int t = 0; t < NT; t += 2) {  // NT even; static reg-set alternation
      body(t, F0, F1);
      body(t + 1, F1, F0);
    }
  }

  if (EPI == 0) {
    const int t3 = n0 / kDim;  // 0:Q 1:K 2:V (uniform per block; 768 = 6*128)
#pragma unroll
    for (int mi = 0; mi < 4; ++mi) {
#pragma unroll
      for (int ni = 0; ni < 4; ++ni) {
        const int gcol = n0 + wc * 64 + ni * 16 + L;
        const int hd = gcol % kDim;
        const int h = hd >> 6, d = hd & 63;
        if (t3 == 2) {
          // V^T with key-permuted 64-blocks: position p stores key s where
          // p = 32(s>>5) + 8((s>>2)&3) + 4((s>>4)&1) + (s&3). The 4 r-values
          // are consecutive keys (s%4==0) -> consecutive positions -> 8B store.
          const int grow = m0 + wr * 64 + mi * 16 + 4 * g;
          const int b = grow >> 10, seq = grow & 1023;
          const int bh = b * kHeads + h;
          const int s6 = seq & 63;  // multiple of 4
          const int p  = 32 * (s6 >> 5) + 8 * ((s6 >> 2) & 3) + 4 * ((s6 >> 4) & 1);
          const int seqp = (seq & ~63) | p;
          uint2 d2;
          d2.x = cvt_pk_bf16(acc[mi][ni][0], acc[mi][ni][1]);
          d2.y = cvt_pk_bf16(acc[mi][ni][2], acc[mi][ni][3]);
          *(uint2*)&VTb[((size_t)bh * 64 + d) * kSeq + seqp] = d2;
        } else {
#pragma unroll
          for (int r = 0; r < 4; ++r) {
            const int grow = m0 + wr * 64 + mi * 16 + 4 * g + r;  // b*1024+seq
            const int b = grow >> 10, seq = grow & 1023;
            const int bh = b * kHeads + h;
            if (t3 == 0) Qb[((size_t)bh * kSeq + seq) * 64 + d] = f2bf(acc[mi][ni][r] * kQSc);
            else         Kb[((size_t)bh * kSeq + seq) * 64 + d] = f2bf(acc[mi][ni][r]);
          }
        }
      }
    }
  } else {
#pragma unroll
    for (int ni = 0; ni < 4; ++ni) {
      const int gcol = n0 + wc * 64 + ni * 16 + L;
      const float bv = bias[gcol];
#pragma unroll
      for (int mi = 0; mi < 4; ++mi) {
#pragma unroll
        for (int r = 0; r < 4; ++r) {
          const int grow = m0 + wr * 64 + mi * 16 + 4 * g + r;
          outF[(size_t)grow * kDim + gcol] = acc[mi][ni][r] + bv;
        }
      }
    }
  }
}

// ---------- flash attention (exact R14 — converged) --------------------------
__global__ __launch_bounds__(256) void attn_kernel(const short* __restrict__ Qb,
                                                   const short* __restrict__ Kb,
                                                   const short* __restrict__ VTb,
                                                   short* __restrict__ AO) {
  __shared__ short Ks[2][64 * 72];   // [key][d]
  __shared__ short VTs[2][64 * 72];  // [d][key-permuted]

  const int tid  = threadIdx.x;
  const int lane = tid & 63, w = tid >> 6;
  const int L = lane & 15, g = lane >> 4;
  const int id = blockIdx.x;
  const int bh = id % 96, qc = id / 96;
  const int q0 = qc * 128 + w * 32;

  const short* Qbase = Qb  + (size_t)bh * kSeq * 64;
  const short* Kbase = Kb  + (size_t)bh * kSeq * 64;
  const short* Vbase = VTb + (size_t)bh * 64 * kSeq;

  short8 qf[2][2];  // Q (pre-scaled by kQSc) as B-operand, resident in regs
#pragma unroll
  for (int qh = 0; qh < 2; ++qh) {
    const short* qp = Qbase + (size_t)(q0 + qh * 16 + L) * 64 + g * 8;
    qf[qh][0] = *(const short8*)qp;
    qf[qh][1] = *(const short8*)(qp + 32);
  }

  f32x4 o[2][4] = {};
  float m_[2] = {-1e30f, -1e30f};  // per-query running max (replicated over g)
  float l_[2] = {0.f, 0.f};        // per-LANE partial sum (reduced at end)

  const int srow = tid >> 2, sc0 = (tid & 3) * 16;  // staging: 16 elems/thread

  {  // prologue: stage tile 0 (V rows copied verbatim — perm is within blocks)
    const short* ksrc = Kbase + (size_t)srow * 64 + sc0;
    const short* vsrc = Vbase + (size_t)srow * kSeq + sc0;
    uint4 k0 = ((const uint4*)ksrc)[0], k1 = ((const uint4*)ksrc)[1];
    uint4 v0 = ((const uint4*)vsrc)[0], v1 = ((const uint4*)vsrc)[1];
    *(uint4*)&Ks[0][srow * 72 + sc0]      = k0;
    *(uint4*)&Ks[0][srow * 72 + sc0 + 8]  = k1;
    *(uint4*)&VTs[0][srow * 72 + sc0]     = v0;
    *(uint4*)&VTs[0][srow * 72 + sc0 + 8] = v1;
  }
  __syncthreads();

  for (int t = 0; t < kSeq / 64; ++t) {
    const int cur = t & 1;
    const bool pf = (t + 1 < kSeq / 64);

    // ---- issue next-tile loads early (T14 async split) ----
    uint4 kr0, kr1, vr0, vr1;
    if (pf) {
      const int kv1 = (t + 1) * 64;
      const short* ksrc = Kbase + (size_t)(kv1 + srow) * 64 + sc0;
      const short* vsrc = Vbase + (size_t)srow * kSeq + kv1 + sc0;
      kr0 = ((const uint4*)ksrc)[0]; kr1 = ((const uint4*)ksrc)[1];
      vr0 = ((const uint4*)vsrc)[0]; vr1 = ((const uint4*)vsrc)[1];
    }

    // ---- K fragments (A-operand) + V fragments (B-operand, pre-permuted) --
    short8 kf[4][2];
#pragma unroll
    for (int nf = 0; nf < 4; ++nf) {
      const short* kp = &Ks[cur][(nf * 16 + L) * 72 + g * 8];
      kf[nf][0] = *(const short8*)kp;
      kf[nf][1] = *(const short8*)(kp + 32);
    }
    short8 vb[4][2];  // hoisted: ds latency hides under QK below
#pragma unroll
    for (int nf = 0; nf < 4; ++nf) {
      const short* vrow = &VTs[cur][(nf * 16 + L) * 72];
      vb[nf][0] = *(const short8*)&vrow[g * 8];
      vb[nf][1] = *(const short8*)&vrow[32 + g * 8];
    }

    // ---- BOTH q-halves' S^T = K @ Q^T issued back-to-back (32 MFMAs) ----
    f32x4 s2[2][4];
    __builtin_amdgcn_s_setprio(1);
#pragma unroll
    for (int qh = 0; qh < 2; ++qh) {
#pragma unroll
      for (int nf = 0; nf < 4; ++nf) {
        f32x4 z = {};
        z = MFMA_B16(kf[nf][0], qf[qh][0], z);
        s2[qh][nf] = MFMA_B16(kf[nf][1], qf[qh][1], z);
      }
    }
    __builtin_amdgcn_s_setprio(0);

    // ---- pipelined per-qh: SM(qh) then immediately PV(qh) (T15) ----------
#pragma unroll
    for (int qh = 0; qh < 2; ++qh) {
      f32x4* s = s2[qh];
      float x0 = fmaxf(fmaxf(s[0][0], s[0][1]), fmaxf(s[0][2], s[0][3]));
      float x1 = fmaxf(fmaxf(s[1][0], s[1][1]), fmaxf(s[1][2], s[1][3]));
      float x2 = fmaxf(fmaxf(s[2][0], s[2][1]), fmaxf(s[2][2], s[2][3]));
      float x3 = fmaxf(fmaxf(s[3][0], s[3][1]), fmaxf(s[3][2], s[3][3]));
      const float mt4 = fmaxf(fmaxf(x0, x1), fmaxf(x2, x3));

      if (__any(mt4 > m_[qh] + 8.0f)) {  // wave-uniform branch (rare)
        float mt = fmaxf(mt4, __shfl_xor(mt4, 16, 64));
        mt = fmaxf(mt, __shfl_xor(mt, 32, 64));          // per-query true max
        const float mnew = fmaxf(m_[qh], mt);
        const float al = __builtin_amdgcn_exp2f(m_[qh] - mnew);
        m_[qh] = mnew;
        l_[qh] *= al;  // per-lane partial: al is query-uniform across g
        float alr[4];
#pragma unroll
        for (int r = 0; r < 4; ++r) alr[r] = __shfl(al, 4 * g + r, 64);
#pragma unroll
        for (int nf = 0; nf < 4; ++nf)
#pragma unroll
          for (int r = 0; r < 4; ++r) o[qh][nf][r] *= alr[r];
      }

      // 4-way parallel rsum partials
      float rs0 = 0.f, rs1 = 0.f, rs2 = 0.f, rs3 = 0.f;
#pragma unroll
      for (int nf = 0; nf < 4; ++nf) {
        float p0 = __builtin_amdgcn_exp2f(s[nf][0] - m_[qh]);
        float p1 = __builtin_amdgcn_exp2f(s[nf][1] - m_[qh]);
        float p2 = __builtin_amdgcn_exp2f(s[nf][2] - m_[qh]);
        float p3 = __builtin_amdgcn_exp2f(s[nf][3] - m_[qh]);
        s[nf][0] = p0; s[nf][1] = p1; s[nf][2] = p2; s[nf][3] = p3;
        rs0 += p0; rs1 += p1; rs2 += p2; rs3 += p3;
      }
      l_[qh] += (rs0 + rs1) + (rs2 + rs3);  // per-lane partial

      U8 t0, t1;
      t0.u[0] = cvt_pk_bf16(s[0][0], s[0][1]);
      t0.u[1] = cvt_pk_bf16(s[0][2], s[0][3]);
      t0.u[2] = cvt_pk_bf16(s[1][0], s[1][1]);
      t0.u[3] = cvt_pk_bf16(s[1][2], s[1][3]);
      t1.u[0] = cvt_pk_bf16(s[2][0], s[2][1]);
      t1.u[1] = cvt_pk_bf16(s[2][2], s[2][3]);
      t1.u[2] = cvt_pk_bf16(s[3][0], s[3][1]);
      t1.u[3] = cvt_pk_bf16(s[3][2], s[3][3]);

      __builtin_amdgcn_s_setprio(1);
#pragma unroll
      for (int nf = 0; nf < 4; ++nf) {
        o[qh][nf] = MFMA_B16(t0.s, vb[nf][0], o[qh][nf]);
        o[qh][nf] = MFMA_B16(t1.s, vb[nf][1], o[qh][nf]);
      }
      __builtin_amdgcn_s_setprio(0);
    }

    // ---- write prefetched tile into other buffer; one barrier per tile ----
    if (pf) {
      *(uint4*)&Ks[cur ^ 1][srow * 72 + sc0]      = kr0;
      *(uint4*)&Ks[cur ^ 1][srow * 72 + sc0 + 8]  = kr1;
      *(uint4*)&VTs[cur ^ 1][srow * 72 + sc0]     = vr0;
      *(uint4*)&VTs[cur ^ 1][srow * 72 + sc0 + 8] = vr1;
    }
    __syncthreads();
  }

  // ---- finalize: reduce l across g-groups ONCE, O /= l, store ----
  const int b = bh / kHeads, h = bh % kHeads;
#pragma unroll
  for (int qh = 0; qh < 2; ++qh) {
    float ls = l_[qh] + __shfl_xor(l_[qh], 16, 64);
    ls += __shfl_xor(ls, 32, 64);  // full per-query sum
    float lq[4];
#pragma unroll
    for (int r = 0; r < 4; ++r) lq[r] = __shfl(ls, 4 * g + r, 64);
    short* aop = AO + ((size_t)(b * kSeq) + q0 + qh * 16) * kDim + h * 64;
#pragma unroll
    for (int r = 0; r < 4; ++r) {
      const float inv = 1.0f / lq[r];
#pragma unroll
      for (int nf = 0; nf < 4; ++nf)
        aop[(size_t)(4 * g + r) * kDim + nf * 16 + L] = f2bf(o[qh][nf][r] * inv);
    }
  }
}

// ---------------------------------------------------------------------------
extern "C" void kernel_launch(void* const* d_in, const int* in_sizes, int n_in,
                              void* d_out, int out_size, void* d_ws, size_t ws_size,
                              hipStream_t stream) {
  const float* x     = (const float*)d_in[0];
  const float* w_in  = (const float*)d_in[1];
  const float* w_out = (const float*)d_in[2];
  const float* b_out = (const float*)d_in[3];
  float* out = (float*)d_out;

  // workspace (bf16 bits as short)
  short* WinT  = (short*)d_ws;                          // [2304][768]
  short* WoutT = WinT  + (size_t)2304 * 768;            // [768][768]
  short* Qb    = WoutT + (size_t)768 * 768;             // [96][1024][64]
  short* Kb    = Qb    + (size_t)96 * 1024 * 64;        // [96][1024][64]
  short* VTb   = Kb    + (size_t)96 * 1024 * 64;        // [96][64][1024] perm'd
  short* AO    = VTb   + (size_t)96 * 1024 * 64;        // [8192][768]

  prep_kernel<<<dim3(1728 + 576), 256, 0, stream>>>(w_in, WinT, w_out, WoutT);

  // gemm1: A = x (f32), cast fused via 3-stage reg pipeline
  gemm_tile<0, 0><<<dim3(8192 / 128, 2304 / 128), 256, 0, stream>>>(
      x, nullptr, WinT, 768, Qb, Kb, VTb, nullptr, nullptr);

  attn_kernel<<<dim3(768), 256, 0, stream>>>(Qb, Kb, VTb, AO);

  // gemm2: A = AO (bf16), proven R8 gload_lds path
  gemm_tile<1, 1><<<dim3(8192 / 128, 768 / 128), 256, 0, stream>>>(
      nullptr, AO, WoutT, 768, nullptr, nullptr, nullptr, b_out, out);
}

// Round 17
// 119.894 us; speedup vs baseline: 1.2418x; 1.2418x over previous
//
#include <hip/hip_runtime.h>

// ---------------------------------------------------------------------------
// MultiHeadedAttention: x[8,1024,768] @ w_in[768,2304] -> qkv -> 12-head attn
// (scale = 768^-0.5) -> concat -> @ w_out[768,768] + b_out. f32 in/out,
// bf16 MFMA internally. R17 = exact revert to R14 (measured best, 120.03 us):
// - prep: merged cast + both weight transposes (1 launch)
// - GEMM: 128x128, BK=32, 3-buffer 2-deep counted-vmcnt gload_lds pipeline
// - attn: q-tile 128, swapped QK^T, P-in-regs via k-perm (V^T stored
//   key-permuted by gemm1 -> V B-frags are 2x ds_read_b128), lazy max,
//   per-lane l partials, SM/PV qh-pipelined.
// R16's fused-cast (2nd attempt) confirmed net-negative: VGPR 76->104 cut
// occupancy, f32 A-reads doubled FETCH. The standalone cast kernel is cheaper.
// ---------------------------------------------------------------------------

using short8 = __attribute__((ext_vector_type(8))) short;  // 8 bf16 (4 VGPR)
using f32x4  = __attribute__((ext_vector_type(4))) float;  // MFMA acc

#define MFMA_B16(a, b, c) __builtin_amdgcn_mfma_f32_16x16x32_bf16((a), (b), (c), 0, 0, 0)

typedef const __attribute__((address_space(1))) void* gvoid_p;
typedef __attribute__((address_space(3))) void* lvoid_p;

constexpr int   kDim   = 768;
constexpr int   kHeads = 12;
constexpr int   kSeq   = 1024;
constexpr float kScale = 0.03608439182435161f;             // 768^-0.5 (full dim)
constexpr float kQSc   = kScale * 1.4426950408889634f;     // fold log2(e) into Q

__device__ __forceinline__ short f2bf(float f) {  // RNE f32 -> bf16 bits
  unsigned u = __float_as_uint(f);
  u += 0x7FFFu + ((u >> 16) & 1u);
  return (short)(u >> 16);
}
__device__ __forceinline__ unsigned cvt_pk_bf16(float lo, float hi) {
  unsigned r;
  asm("v_cvt_pk_bf16_f32 %0, %1, %2" : "=v"(r) : "v"(lo), "v"(hi));
  return r;
}
union U8 { unsigned u[4]; short8 s; };

// ---------- merged prep: x cast (blocks 0..3071), w_in^T (next 1728),
// ----------              w_out^T (last 576). One launch instead of three.
__global__ __launch_bounds__(256) void prep_kernel(const float* __restrict__ x,
                                                   short* __restrict__ xbf,
                                                   const float* __restrict__ w_in,
                                                   short* __restrict__ WinT,
                                                   const float* __restrict__ w_out,
                                                   short* __restrict__ WoutT) {
  __shared__ float tile[32][33];
  const int bid = blockIdx.x;
  if (bid < 3072) {  // cast: one short8 per thread
    const int i = bid * 256 + threadIdx.x;
    float4 a = ((const float4*)x)[i * 2];
    float4 b = ((const float4*)x)[i * 2 + 1];
    short8 s;
    s[0] = f2bf(a.x); s[1] = f2bf(a.y); s[2] = f2bf(a.z); s[3] = f2bf(a.w);
    s[4] = f2bf(b.x); s[5] = f2bf(b.y); s[6] = f2bf(b.z); s[7] = f2bf(b.w);
    ((short8*)xbf)[i] = s;
    return;
  }
  // transpose+cvt: out[c][r] = bf16(in[r][c])
  const float* in; short* out; int R, C, bx, by;
  if (bid < 3072 + 1728) {
    const int b2 = bid - 3072;
    in = w_in; out = WinT; R = 768; C = 2304; bx = b2 % 72; by = b2 / 72;
  } else {
    const int b2 = bid - 4800;
    in = w_out; out = WoutT; R = 768; C = 768; bx = b2 % 24; by = b2 / 24;
  }
  const int c0 = bx * 32, r0 = by * 32;
  const int tx = threadIdx.x & 31, ty = threadIdx.x >> 5;
#pragma unroll
  for (int i = 0; i < 32; i += 8)
    tile[ty + i][tx] = in[(size_t)(r0 + ty + i) * C + c0 + tx];
  __syncthreads();
#pragma unroll
  for (int i = 0; i < 32; i += 8)
    out[(size_t)(c0 + ty + i) * R + r0 + tx] = f2bf(tile[tx][ty + i]);
}

// ---------- 128x128 MFMA GEMM, BK=32, 4 waves, 3-buf 2-deep counted-vmcnt --
// (exact R8/R13 structure — measured best; do not touch)
template <int EPI>
__global__ __launch_bounds__(256) void gemm_tile(const short* __restrict__ A,
                                                 const short* __restrict__ BT,
                                                 int Kd,
                                                 short* __restrict__ Qb,
                                                 short* __restrict__ Kb,
                                                 short* __restrict__ VTb,
                                                 const float* __restrict__ bias,
                                                 float* __restrict__ outF) {
  __shared__ short As[3][128 * 32];
  __shared__ short Bs[3][128 * 32];

  const int tid  = threadIdx.x;
  const int lane = tid & 63, w = tid >> 6;
  const int L = lane & 15, g = lane >> 4;
  const int wr = w >> 1, wc = w & 1;
  const int m0 = blockIdx.x * 128, n0 = blockIdx.y * 128;

  const int r4 = lane >> 2;        // row within 16-row chunk
  const int c8 = (lane & 3) * 8;   // k-col (shorts)

  auto stage = [&](int buf, int k0) {  // 4 gload_lds per wave (vmcnt +4)
#pragma unroll
    for (int c = 0; c < 2; ++c) {
      const short* ag = A  + (size_t)(m0 + w * 32 + c * 16 + r4) * Kd + k0 + c8;
      const short* bg = BT + (size_t)(n0 + w * 32 + c * 16 + r4) * Kd + k0 + c8;
      __builtin_amdgcn_global_load_lds((gvoid_p)ag, (lvoid_p)&As[buf][(w * 2 + c) * 512], 16, 0, 0);
      __builtin_amdgcn_global_load_lds((gvoid_p)bg, (lvoid_p)&Bs[buf][(w * 2 + c) * 512], 16, 0, 0);
    }
  };

  f32x4 acc[4][4] = {};

  stage(0, 0);
  stage(1, 32);

  const int NT = Kd / 32;
  for (int t = 0; t < NT; ++t) {
    const int cur = t % 3;
    if (t + 2 < NT) stage((t + 2) % 3, (t + 2) * 32);

    // wait for tile t only; tiles t+1, t+2 (8 loads) stay in flight
    if (t + 2 < NT)      asm volatile("s_waitcnt vmcnt(8)" ::: "memory");
    else if (t + 1 < NT) asm volatile("s_waitcnt vmcnt(4)" ::: "memory");
    else                 asm volatile("s_waitcnt vmcnt(0)" ::: "memory");
    __builtin_amdgcn_s_barrier();  // all waves' tile-t loads landed

    short8 af[4], bfr[4];
#pragma unroll
    for (int mi = 0; mi < 4; ++mi)
      af[mi] = *(const short8*)&As[cur][(wr * 64 + mi * 16 + L) * 32 + g * 8];
#pragma unroll
    for (int ni = 0; ni < 4; ++ni)
      bfr[ni] = *(const short8*)&Bs[cur][(wc * 64 + ni * 16 + L) * 32 + g * 8];
#pragma unroll
    for (int mi = 0; mi < 4; ++mi)
#pragma unroll
      for (int ni = 0; ni < 4; ++ni)
        acc[mi][ni] = MFMA_B16(af[mi], bfr[ni], acc[mi][ni]);

    asm volatile("" ::: "memory");
    __builtin_amdgcn_s_barrier();  // reads done before next stage overwrites
  }

  if (EPI == 0) {
    const int t3 = n0 / kDim;  // 0:Q 1:K 2:V (uniform per block; 768 = 6*128)
#pragma unroll
    for (int mi = 0; mi < 4; ++mi) {
#pragma unroll
      for (int ni = 0; ni < 4; ++ni) {
        const int gcol = n0 + wc * 64 + ni * 16 + L;
        const int hd = gcol % kDim;
        const int h = hd >> 6, d = hd & 63;
        if (t3 == 2) {
          // V^T with key-permuted 64-blocks: position p stores key s where
          // p = 32(s>>5) + 8((s>>2)&3) + 4((s>>4)&1) + (s&3). The 4 r-values
          // are consecutive keys (s%4==0) -> consecutive positions -> 8B store.
          const int grow = m0 + wr * 64 + mi * 16 + 4 * g;
          const int b = grow >> 10, seq = grow & 1023;
          const int bh = b * kHeads + h;
          const int s6 = seq & 63;  // multiple of 4
          const int p  = 32 * (s6 >> 5) + 8 * ((s6 >> 2) & 3) + 4 * ((s6 >> 4) & 1);
          const int seqp = (seq & ~63) | p;
          uint2 d2;
          d2.x = cvt_pk_bf16(acc[mi][ni][0], acc[mi][ni][1]);
          d2.y = cvt_pk_bf16(acc[mi][ni][2], acc[mi][ni][3]);
          *(uint2*)&VTb[((size_t)bh * 64 + d) * kSeq + seqp] = d2;
        } else {
#pragma unroll
          for (int r = 0; r < 4; ++r) {
            const int grow = m0 + wr * 64 + mi * 16 + 4 * g + r;  // b*1024+seq
            const int b = grow >> 10, seq = grow & 1023;
            const int bh = b * kHeads + h;
            if (t3 == 0) Qb[((size_t)bh * kSeq + seq) * 64 + d] = f2bf(acc[mi][ni][r] * kQSc);
            else         Kb[((size_t)bh * kSeq + seq) * 64 + d] = f2bf(acc[mi][ni][r]);
          }
        }
      }
    }
  } else {
#pragma unroll
    for (int ni = 0; ni < 4; ++ni) {
      const int gcol = n0 + wc * 64 + ni * 16 + L;
      const float bv = bias[gcol];
#pragma unroll
      for (int mi = 0; mi < 4; ++mi) {
#pragma unroll
        for (int r = 0; r < 4; ++r) {
          const int grow = m0 + wr * 64 + mi * 16 + 4 * g + r;
          outF[(size_t)grow * kDim + gcol] = acc[mi][ni][r] + bv;
        }
      }
    }
  }
}

// ---------- flash attention (R13 + qh-pipelined SM/PV — measured best) ------
__global__ __launch_bounds__(256) void attn_kernel(const short* __restrict__ Qb,
                                                   const short* __restrict__ Kb,
                                                   const short* __restrict__ VTb,
                                                   short* __restrict__ AO) {
  __shared__ short Ks[2][64 * 72];   // [key][d]
  __shared__ short VTs[2][64 * 72];  // [d][key-permuted]

  const int tid  = threadIdx.x;
  const int lane = tid & 63, w = tid >> 6;
  const int L = lane & 15, g = lane >> 4;
  const int id = blockIdx.x;
  const int bh = id % 96, qc = id / 96;
  const int q0 = qc * 128 + w * 32;

  const short* Qbase = Qb  + (size_t)bh * kSeq * 64;
  const short* Kbase = Kb  + (size_t)bh * kSeq * 64;
  const short* Vbase = VTb + (size_t)bh * 64 * kSeq;

  short8 qf[2][2];  // Q (pre-scaled by kQSc) as B-operand, resident in regs
#pragma unroll
  for (int qh = 0; qh < 2; ++qh) {
    const short* qp = Qbase + (size_t)(q0 + qh * 16 + L) * 64 + g * 8;
    qf[qh][0] = *(const short8*)qp;
    qf[qh][1] = *(const short8*)(qp + 32);
  }

  f32x4 o[2][4] = {};
  float m_[2] = {-1e30f, -1e30f};  // per-query running max (replicated over g)
  float l_[2] = {0.f, 0.f};        // per-LANE partial sum (reduced at end)

  const int srow = tid >> 2, sc0 = (tid & 3) * 16;  // staging: 16 elems/thread

  {  // prologue: stage tile 0 (V rows copied verbatim — perm is within blocks)
    const short* ksrc = Kbase + (size_t)srow * 64 + sc0;
    const short* vsrc = Vbase + (size_t)srow * kSeq + sc0;
    uint4 k0 = ((const uint4*)ksrc)[0], k1 = ((const uint4*)ksrc)[1];
    uint4 v0 = ((const uint4*)vsrc)[0], v1 = ((const uint4*)vsrc)[1];
    *(uint4*)&Ks[0][srow * 72 + sc0]      = k0;
    *(uint4*)&Ks[0][srow * 72 + sc0 + 8]  = k1;
    *(uint4*)&VTs[0][srow * 72 + sc0]     = v0;
    *(uint4*)&VTs[0][srow * 72 + sc0 + 8] = v1;
  }
  __syncthreads();

  for (int t = 0; t < kSeq / 64; ++t) {
    const int cur = t & 1;
    const bool pf = (t + 1 < kSeq / 64);

    // ---- issue next-tile loads early (T14 async split) ----
    uint4 kr0, kr1, vr0, vr1;
    if (pf) {
      const int kv1 = (t + 1) * 64;
      const short* ksrc = Kbase + (size_t)(kv1 + srow) * 64 + sc0;
      const short* vsrc = Vbase + (size_t)srow * kSeq + kv1 + sc0;
      kr0 = ((const uint4*)ksrc)[0]; kr1 = ((const uint4*)ksrc)[1];
      vr0 = ((const uint4*)vsrc)[0]; vr1 = ((const uint4*)vsrc)[1];
    }

    // ---- K fragments (A-operand) + V fragments (B-operand, pre-permuted) --
    short8 kf[4][2];
#pragma unroll
    for (int nf = 0; nf < 4; ++nf) {
      const short* kp = &Ks[cur][(nf * 16 + L) * 72 + g * 8];
      kf[nf][0] = *(const short8*)kp;
      kf[nf][1] = *(const short8*)(kp + 32);
    }
    short8 vb[4][2];  // hoisted: ds latency hides under QK below
#pragma unroll
    for (int nf = 0; nf < 4; ++nf) {
      const short* vrow = &VTs[cur][(nf * 16 + L) * 72];
      vb[nf][0] = *(const short8*)&vrow[g * 8];
      vb[nf][1] = *(const short8*)&vrow[32 + g * 8];
    }

    // ---- BOTH q-halves' S^T = K @ Q^T issued back-to-back (32 MFMAs) ----
    f32x4 s2[2][4];
    __builtin_amdgcn_s_setprio(1);
#pragma unroll
    for (int qh = 0; qh < 2; ++qh) {
#pragma unroll
      for (int nf = 0; nf < 4; ++nf) {
        f32x4 z = {};
        z = MFMA_B16(kf[nf][0], qf[qh][0], z);
        s2[qh][nf] = MFMA_B16(kf[nf][1], qf[qh][1], z);
      }
    }
    __builtin_amdgcn_s_setprio(0);

    // ---- pipelined per-qh: SM(qh) then immediately PV(qh) (T15) ----------
#pragma unroll
    for (int qh = 0; qh < 2; ++qh) {
      f32x4* s = s2[qh];
      float x0 = fmaxf(fmaxf(s[0][0], s[0][1]), fmaxf(s[0][2], s[0][3]));
      float x1 = fmaxf(fmaxf(s[1][0], s[1][1]), fmaxf(s[1][2], s[1][3]));
      float x2 = fmaxf(fmaxf(s[2][0], s[2][1]), fmaxf(s[2][2], s[2][3]));
      float x3 = fmaxf(fmaxf(s[3][0], s[3][1]), fmaxf(s[3][2], s[3][3]));
      const float mt4 = fmaxf(fmaxf(x0, x1), fmaxf(x2, x3));

      if (__any(mt4 > m_[qh] + 8.0f)) {  // wave-uniform branch (rare)
        float mt = fmaxf(mt4, __shfl_xor(mt4, 16, 64));
        mt = fmaxf(mt, __shfl_xor(mt, 32, 64));          // per-query true max
        const float mnew = fmaxf(m_[qh], mt);
        const float al = __builtin_amdgcn_exp2f(m_[qh] - mnew);
        m_[qh] = mnew;
        l_[qh] *= al;  // per-lane partial: al is query-uniform across g
        float alr[4];
#pragma unroll
        for (int r = 0; r < 4; ++r) alr[r] = __shfl(al, 4 * g + r, 64);
#pragma unroll
        for (int nf = 0; nf < 4; ++nf)
#pragma unroll
          for (int r = 0; r < 4; ++r) o[qh][nf][r] *= alr[r];
      }

      // 4-way parallel rsum partials
      float rs0 = 0.f, rs1 = 0.f, rs2 = 0.f, rs3 = 0.f;
#pragma unroll
      for (int nf = 0; nf < 4; ++nf) {
        float p0 = __builtin_amdgcn_exp2f(s[nf][0] - m_[qh]);
        float p1 = __builtin_amdgcn_exp2f(s[nf][1] - m_[qh]);
        float p2 = __builtin_amdgcn_exp2f(s[nf][2] - m_[qh]);
        float p3 = __builtin_amdgcn_exp2f(s[nf][3] - m_[qh]);
        s[nf][0] = p0; s[nf][1] = p1; s[nf][2] = p2; s[nf][3] = p3;
        rs0 += p0; rs1 += p1; rs2 += p2; rs3 += p3;
      }
      l_[qh] += (rs0 + rs1) + (rs2 + rs3);  // per-lane partial

      U8 t0, t1;
      t0.u[0] = cvt_pk_bf16(s[0][0], s[0][1]);
      t0.u[1] = cvt_pk_bf16(s[0][2], s[0][3]);
      t0.u[2] = cvt_pk_bf16(s[1][0], s[1][1]);
      t0.u[3] = cvt_pk_bf16(s[1][2], s[1][3]);
      t1.u[0] = cvt_pk_bf16(s[2][0], s[2][1]);
      t1.u[1] = cvt_pk_bf16(s[2][2], s[2][3]);
      t1.u[2] = cvt_pk_bf16(s[3][0], s[3][1]);
      t1.u[3] = cvt_pk_bf16(s[3][2], s[3][3]);

      __builtin_amdgcn_s_setprio(1);
#pragma unroll
      for (int nf = 0; nf < 4; ++nf) {
        o[qh][nf] = MFMA_B16(t0.s, vb[nf][0], o[qh][nf]);
        o[qh][nf] = MFMA_B16(t1.s, vb[nf][1], o[qh][nf]);
      }
      __builtin_amdgcn_s_setprio(0);
    }

    // ---- write prefetched tile into other buffer; one barrier per tile ----
    if (pf) {
      *(uint4*)&Ks[cur ^ 1][srow * 72 + sc0]      = kr0;
      *(uint4*)&Ks[cur ^ 1][srow * 72 + sc0 + 8]  = kr1;
      *(uint4*)&VTs[cur ^ 1][srow * 72 + sc0]     = vr0;
      *(uint4*)&VTs[cur ^ 1][srow * 72 + sc0 + 8] = vr1;
    }
    __syncthreads();
  }

  // ---- finalize: reduce l across g-groups ONCE, O /= l, store ----
  const int b = bh / kHeads, h = bh % kHeads;
#pragma unroll
  for (int qh = 0; qh < 2; ++qh) {
    float ls = l_[qh] + __shfl_xor(l_[qh], 16, 64);
    ls += __shfl_xor(ls, 32, 64);  // full per-query sum
    float lq[4];
#pragma unroll
    for (int r = 0; r < 4; ++r) lq[r] = __shfl(ls, 4 * g + r, 64);
    short* aop = AO + ((size_t)(b * kSeq) + q0 + qh * 16) * kDim + h * 64;
#pragma unroll
    for (int r = 0; r < 4; ++r) {
      const float inv = 1.0f / lq[r];
#pragma unroll
      for (int nf = 0; nf < 4; ++nf)
        aop[(size_t)(4 * g + r) * kDim + nf * 16 + L] = f2bf(o[qh][nf][r] * inv);
    }
  }
}

// ---------------------------------------------------------------------------
extern "C" void kernel_launch(void* const* d_in, const int* in_sizes, int n_in,
                              void* d_out, int out_size, void* d_ws, size_t ws_size,
                              hipStream_t stream) {
  const float* x     = (const float*)d_in[0];
  const float* w_in  = (const float*)d_in[1];
  const float* w_out = (const float*)d_in[2];
  const float* b_out = (const float*)d_in[3];
  float* out = (float*)d_out;

  // workspace (bf16 as short). xbf aliases AO: xbf dead before attn writes AO.
  short* WinT  = (short*)d_ws;                          // [2304][768]
  short* WoutT = WinT  + (size_t)2304 * 768;            // [768][768]
  short* Qb    = WoutT + (size_t)768 * 768;             // [96][1024][64]
  short* Kb    = Qb    + (size_t)96 * 1024 * 64;        // [96][1024][64]
  short* VTb   = Kb    + (size_t)96 * 1024 * 64;        // [96][64][1024] perm'd
  short* AO    = VTb   + (size_t)96 * 1024 * 64;        // [8192][768]
  short* xbf   = AO;                                    // alias (see above)

  prep_kernel<<<dim3(3072 + 1728 + 576), 256, 0, stream>>>(
      x, xbf, w_in, WinT, w_out, WoutT);

  gemm_tile<0><<<dim3(8192 / 128, 2304 / 128), 256, 0, stream>>>(
      xbf, WinT, 768, Qb, Kb, VTb, nullptr, nullptr);

  attn_kernel<<<dim3(768), 256, 0, stream>>>(Qb, Kb, VTb, AO);

  gemm_tile<1><<<dim3(8192 / 128, 768 / 128), 256, 0, stream>>>(
      AO, WoutT, 768, nullptr, nullptr, nullptr, b_out, out);
}